// Round 6
// baseline (339.420 us; speedup 1.0000x reference)
//
#include <hip/hip_runtime.h>
#include <math.h>

// ---------------------------------------------------------------------------
// GAT 2-layer (PyG GATConv eval) on gfx950.
// R6: max-free softmax in both agg kernels (inputs bounded -> exp safe),
//     log2e folded into alpha coefficients so exp is a bare v_exp_f32.
// R5: MFMA bf16 GEMMs. R4: parallel scan. R3: bf16 payload gathers.
// ---------------------------------------------------------------------------

typedef unsigned short u16;
typedef short s8v __attribute__((ext_vector_type(8)));    // 8 bf16 (4 VGPR)
typedef float f32x4 __attribute__((ext_vector_type(4)));  // MFMA acc

#define LOG2E 1.4426950408889634f

__device__ __forceinline__ float bflo(unsigned int u) {
  return __builtin_bit_cast(float, u << 16);
}
__device__ __forceinline__ float bfhi(unsigned int u) {
  return __builtin_bit_cast(float, u & 0xffff0000u);
}
__device__ __forceinline__ u16 f2bf(float f) {  // RNE
  unsigned int u = __builtin_bit_cast(unsigned int, f);
  return (u16)((u + 0x7fff + ((u >> 16) & 1)) >> 16);
}

// ---- CSR build ------------------------------------------------------------

__global__ void count_edges_kernel(const int* __restrict__ ei, int E, int Nn,
                                   int* __restrict__ deg) {
  int e = blockIdx.x * blockDim.x + threadIdx.x;
  if (e >= E + Nn) return;
  int dst = (e < E) ? ei[E + e] : (e - E);  // self-loops appended
  atomicAdd(&deg[dst], 1);
}

__global__ void scan_partials_kernel(const int* __restrict__ deg,
                                     int* __restrict__ partials, int Ntot) {
  __shared__ int red[256];
  int t = threadIdx.x;
  int base = blockIdx.x * 1024 + t * 4;
  int s = 0;
  if (base + 3 < Ntot) {
    int4 v = *(const int4*)(deg + base);
    s = v.x + v.y + v.z + v.w;
  } else {
    for (int i = 0; i < 4; ++i)
      if (base + i < Ntot) s += deg[base + i];
  }
  red[t] = s;
  __syncthreads();
  for (int off = 128; off > 0; off >>= 1) {
    if (t < off) red[t] += red[t + off];
    __syncthreads();
  }
  if (t == 0) partials[blockIdx.x] = red[0];
}

__global__ void scan_top_kernel(int* __restrict__ partials, int NB) {
  __shared__ int sh[256];
  int t = threadIdx.x;
  sh[t] = (t < NB) ? partials[t] : 0;
  __syncthreads();
  for (int off = 1; off < 256; off <<= 1) {
    int v = (t >= off) ? sh[t - off] : 0;
    __syncthreads();
    sh[t] += v;
    __syncthreads();
  }
  if (t < NB) partials[t] = (t == 0) ? 0 : sh[t - 1];
}

__global__ void scan_final_kernel(const int* __restrict__ deg,
                                  const int* __restrict__ partials,
                                  int* __restrict__ rowptr,
                                  int* __restrict__ cursor, int Ntot) {
  __shared__ int sums[256];
  int t = threadIdx.x;
  int base = blockIdx.x * 1024 + t * 4;
  int4 v = make_int4(0, 0, 0, 0);
  if (base + 3 < Ntot) {
    v = *(const int4*)(deg + base);
  } else {
    if (base + 0 < Ntot) v.x = deg[base + 0];
    if (base + 1 < Ntot) v.y = deg[base + 1];
    if (base + 2 < Ntot) v.z = deg[base + 2];
    if (base + 3 < Ntot) v.w = deg[base + 3];
  }
  sums[t] = v.x + v.y + v.z + v.w;
  __syncthreads();
  for (int off = 1; off < 256; off <<= 1) {
    int u = (t >= off) ? sums[t - off] : 0;
    __syncthreads();
    sums[t] += u;
    __syncthreads();
  }
  int excl = partials[blockIdx.x] + ((t == 0) ? 0 : sums[t - 1]);
  int4 r;
  r.x = excl;
  r.y = r.x + v.x;
  r.z = r.y + v.y;
  r.w = r.z + v.z;
  if (base + 3 < Ntot) {
    *(int4*)(rowptr + base) = r;
    *(int4*)(cursor + base) = r;
  } else {
    if (base + 0 < Ntot) { rowptr[base + 0] = r.x; cursor[base + 0] = r.x; }
    if (base + 1 < Ntot) { rowptr[base + 1] = r.y; cursor[base + 1] = r.y; }
    if (base + 2 < Ntot) { rowptr[base + 2] = r.z; cursor[base + 2] = r.z; }
    if (base + 3 < Ntot) { rowptr[base + 3] = r.w; cursor[base + 3] = r.w; }
  }
}

__global__ void scatter_edges_kernel(const int* __restrict__ ei, int E, int Nn,
                                     int* __restrict__ cursor, int* __restrict__ col) {
  int e = blockIdx.x * blockDim.x + threadIdx.x;
  if (e >= E + Nn) return;
  int src, dst;
  if (e < E) { src = ei[e]; dst = ei[E + e]; }
  else       { src = dst = e - E; }
  int pos = atomicAdd(&cursor[dst], 1);
  col[pos] = src;
}

// ---- prep: cast x -> bf16; transpose W1, W2 -> [N][K] bf16 ------------------

__global__ void cast_prep_kernel(const float* __restrict__ x, u16* __restrict__ xb,
                                 int nx4,
                                 const float* __restrict__ W1, u16* __restrict__ W1T,
                                 int K1, int N1,
                                 const float* __restrict__ W2, u16* __restrict__ W2T,
                                 int K2, int N2) {
  int i = blockIdx.x * blockDim.x + threadIdx.x;
  if (i < nx4) {
    float4 v = *(const float4*)(x + (size_t)i * 4);
    ushort4 o = make_ushort4(f2bf(v.x), f2bf(v.y), f2bf(v.z), f2bf(v.w));
    *(ushort4*)(xb + (size_t)i * 4) = o;
    return;
  }
  int e = i - nx4;
  int tot1 = K1 * N1;
  if (e < tot1) {
    int k = e / N1, n = e % N1;
    W1T[n * K1 + k] = f2bf(W1[e]);
    return;
  }
  e -= tot1;
  if (e < K2 * N2) {
    int k = e / N2, n = e % N2;
    W2T[n * K2 + k] = f2bf(W2[e]);
  }
}

// ---- MFMA bf16 GEMM: C[M][NC](bf16) = A[Mpad][K](bf16) @ Bt[N][K](bf16)^T ---
// BM=128, BK=32, 256 threads = 4 waves (2x2). Wave tile 64 x (BN/2).

template <int BN>
__global__ __launch_bounds__(256) void gemm_mfma_kernel(
    const u16* __restrict__ A, const u16* __restrict__ Bt,
    u16* __restrict__ C, int M, int K, int NC) {
  constexpr int BM = 128, BK = 32, PK = 40;
  constexpr int NJ = BN / 32;  // frags per wave in N (BN=128 -> 4, 64 -> 2)
  __shared__ short As[BM][PK];
  __shared__ short Bs[BN][PK];

  int tid = threadIdx.x;
  int lane = tid & 63, w = tid >> 6;
  int wm = (w >> 1) * 64, wn = (w & 1) * (BN / 2);
  int bm0 = blockIdx.x * BM, bn0 = blockIdx.y * BN;
  int fr = lane & 15, fk = (lane >> 4) * 8;

  f32x4 acc[4][NJ] = {};

  for (int k0 = 0; k0 < K; k0 += BK) {
#pragma unroll
    for (int p = 0; p < BM * BK / 2048; ++p) {
      int idx = p * 2048 + tid * 8;
      int r = idx / BK, c = idx % BK;
      *(s8v*)&As[r][c] = *(const s8v*)(A + (size_t)(bm0 + r) * K + k0 + c);
    }
#pragma unroll
    for (int p = 0; p < BN * BK / 2048; ++p) {
      int idx = p * 2048 + tid * 8;
      int r = idx / BK, c = idx % BK;
      *(s8v*)&Bs[r][c] = *(const s8v*)(Bt + (size_t)(bn0 + r) * K + k0 + c);
    }
    __syncthreads();

    s8v af[4], bf[NJ];
#pragma unroll
    for (int i = 0; i < 4; ++i)
      af[i] = *(const s8v*)&As[wm + i * 16 + fr][fk];
#pragma unroll
    for (int j = 0; j < NJ; ++j)
      bf[j] = *(const s8v*)&Bs[wn + j * 16 + fr][fk];
#pragma unroll
    for (int i = 0; i < 4; ++i)
#pragma unroll
      for (int j = 0; j < NJ; ++j)
        acc[i][j] = __builtin_amdgcn_mfma_f32_16x16x32_bf16(af[i], bf[j], acc[i][j], 0, 0, 0);
    __syncthreads();
  }

#pragma unroll
  for (int i = 0; i < 4; ++i)
#pragma unroll
    for (int j = 0; j < NJ; ++j)
#pragma unroll
      for (int r = 0; r < 4; ++r) {
        int row = bm0 + wm + i * 16 + (lane >> 4) * 4 + r;
        if (row < M)
          C[(size_t)row * NC + bn0 + wn + j * 16 + fr] = f2bf(acc[i][j][r]);
      }
}

// ---- per-node attention coefficients (bf16 xl) ------------------------------
// NOTE: outputs pre-scaled by log2(e) so agg kernels can use exp2f directly.
// lrelu commutes with positive scaling, softmax is unchanged.

__global__ void alpha_kernel(const u16* __restrict__ xlb,
                             const float* __restrict__ a_src,
                             const float* __restrict__ a_dst,
                             float* __restrict__ asrc, float* __restrict__ adst,
                             int NH, int H, int C) {
  int idx = blockIdx.x * blockDim.x + threadIdx.x;  // (n,h)
  if (idx >= NH) return;
  int h = idx % H;
  const u16* row = xlb + (size_t)idx * C;
  float ssum = 0.f, dsum = 0.f;
  for (int c = 0; c < C; c += 8) {
    uint4 v = *(const uint4*)(row + c);
    float f[8] = {bflo(v.x), bfhi(v.x), bflo(v.y), bfhi(v.y),
                  bflo(v.z), bfhi(v.z), bflo(v.w), bfhi(v.w)};
#pragma unroll
    for (int j = 0; j < 8; ++j) {
      ssum = fmaf(f[j], a_src[h * C + c + j], ssum);
      dsum = fmaf(f[j], a_dst[h * C + c + j], dsum);
    }
  }
  asrc[idx] = ssum * LOG2E;
  adst[idx] = dsum * LOG2E;
}

// ---- layer-1 aggregation: H=4, C=64, wave/node, depth-2 pipeline ------------
// Max-free softmax: inputs bounded (|e| << 80), fp32 exp cannot overflow.
// epilogue: +bias, ELU, write h as bf16 (feeds GEMM2)

__global__ void agg_multi_kernel(const u16* __restrict__ xlb,
                                 const float* __restrict__ asrc,
                                 const float* __restrict__ adst,
                                 const int* __restrict__ rowptr,
                                 const int* __restrict__ col,
                                 const float* __restrict__ bias,
                                 u16* __restrict__ hb, int Nn) {
  int n = blockIdx.x * (blockDim.x >> 6) + (threadIdx.x >> 6);
  if (n >= Nn) return;
  int lane = threadIdx.x & 63;
  int h = lane >> 4;
  float adn = adst[n * 4 + h];
  int beg = rowptr[n], end = rowptr[n + 1];

  float s = 0.f;
  float4 acc = make_float4(0.f, 0.f, 0.f, 0.f);

  float as0 = 0.f, as1 = 0.f;
  uint2 v0 = make_uint2(0, 0), v1 = make_uint2(0, 0);
  {
    int sc = col[beg];
    as0 = asrc[sc * 4 + h];
    v0 = *(const uint2*)(xlb + (size_t)sc * 256 + lane * 4);
    if (beg + 1 < end) {
      int sc1 = col[beg + 1];
      as1 = asrc[sc1 * 4 + h];
      v1 = *(const uint2*)(xlb + (size_t)sc1 * 256 + lane * 4);
    }
  }

  for (int i = beg; i < end; ++i) {
    float e = as0 + adn;
    e = fmaxf(e, 0.2f * e);                   // leaky_relu 0.2 (log2-scaled)
    uint2 vc = v0;
    as0 = as1; v0 = v1;                       // shift pipeline
    if (i + 2 < end) {
      int sc2 = col[i + 2];
      as1 = asrc[sc2 * 4 + h];
      v1 = *(const uint2*)(xlb + (size_t)sc2 * 256 + lane * 4);
    }
    float w = exp2f(e);
    s += w;
    acc.x = fmaf(w, bflo(vc.x), acc.x);
    acc.y = fmaf(w, bfhi(vc.x), acc.y);
    acc.z = fmaf(w, bflo(vc.y), acc.z);
    acc.w = fmaf(w, bfhi(vc.y), acc.w);
  }
  float inv_s = 1.f / s;

  float4 b = *(const float4*)(bias + lane * 4);
  float4 o;
  o.x = fmaf(acc.x, inv_s, b.x);
  o.y = fmaf(acc.y, inv_s, b.y);
  o.z = fmaf(acc.z, inv_s, b.z);
  o.w = fmaf(acc.w, inv_s, b.w);
  o.x = (o.x > 0.f) ? o.x : __expf(o.x) - 1.f;  // ELU
  o.y = (o.y > 0.f) ? o.y : __expf(o.y) - 1.f;
  o.z = (o.z > 0.f) ? o.z : __expf(o.z) - 1.f;
  o.w = (o.w > 0.f) ? o.w : __expf(o.w) - 1.f;
  ushort4 ov = make_ushort4(f2bf(o.x), f2bf(o.y), f2bf(o.z), f2bf(o.w));
  *(ushort4*)(hb + (size_t)n * 256 + lane * 4) = ov;
}

// ---- layer-2 aggregation: H=1, C=64, wave/node, depth-4 pipeline ------------

__global__ void agg_single_kernel(const u16* __restrict__ xlb,
                                  const float* __restrict__ asrc,
                                  const float* __restrict__ adst,
                                  const int* __restrict__ rowptr,
                                  const int* __restrict__ col,
                                  const float* __restrict__ bias,
                                  float* __restrict__ out, int Nn) {
  int n = blockIdx.x * (blockDim.x >> 6) + (threadIdx.x >> 6);
  if (n >= Nn) return;
  int lane = threadIdx.x & 63;
  float adn = adst[n];
  int beg = rowptr[n], end = rowptr[n + 1];
  int d = end - beg;

  float s = 0.f, acc = 0.f;

  float as0 = 0.f, as1 = 0.f, as2 = 0.f, as3 = 0.f;
  u16 w0 = 0, w1 = 0, w2 = 0, w3 = 0;
  {
    int sc = col[beg];
    as0 = asrc[sc]; w0 = xlb[(size_t)sc * 64 + lane];
    if (d > 1) { sc = col[beg + 1]; as1 = asrc[sc]; w1 = xlb[(size_t)sc * 64 + lane]; }
    if (d > 2) { sc = col[beg + 2]; as2 = asrc[sc]; w2 = xlb[(size_t)sc * 64 + lane]; }
    if (d > 3) { sc = col[beg + 3]; as3 = asrc[sc]; w3 = xlb[(size_t)sc * 64 + lane]; }
  }

  for (int i = beg; i < end; ++i) {
    float e = as0 + adn;
    e = fmaxf(e, 0.2f * e);
    float vc = bflo((unsigned int)w0);
    as0 = as1; w0 = w1;                       // shift pipeline
    as1 = as2; w1 = w2;
    as2 = as3; w2 = w3;
    if (i + 4 < end) {
      int sc = col[i + 4];
      as3 = asrc[sc];
      w3 = xlb[(size_t)sc * 64 + lane];
    }
    float w = exp2f(e);
    s += w;
    acc = fmaf(w, vc, acc);
  }
  out[(size_t)n * 64 + lane] = fmaf(acc, 1.f / s, bias[lane]);
}

// ---------------------------------------------------------------------------

extern "C" void kernel_launch(void* const* d_in, const int* in_sizes, int n_in,
                              void* d_out, int out_size, void* d_ws, size_t ws_size,
                              hipStream_t stream) {
  const float* x   = (const float*)d_in[0];
  const int*   ei  = (const int*)d_in[1];
  const float* W1  = (const float*)d_in[2];
  const float* as1 = (const float*)d_in[3];
  const float* ad1 = (const float*)d_in[4];
  const float* b1  = (const float*)d_in[5];
  const float* W2  = (const float*)d_in[6];
  const float* as2 = (const float*)d_in[7];
  const float* ad2 = (const float*)d_in[8];
  const float* b2  = (const float*)d_in[9];
  float* out = (float*)d_out;

  const int Nn = in_sizes[0] / 128;  // 50000
  const int E  = in_sizes[1] / 2;    // 800000
  const int Et = E + Nn;
  const int Ntot = Nn + 1;           // scan domain (virtual deg[Nn]=0)
  const int NB = (Ntot + 1023) / 1024;
  const int MB = (Nn + 127) / 128;   // GEMM row blocks
  const int Mpad = MB * 128;         // padded rows so staging reads stay in-bounds

  char* base = (char*)d_ws;
  size_t off = 0;
  auto alloc = [&](size_t bytes) -> void* {
    void* p = base + off;
    off = (off + bytes + 255) & ~(size_t)255;
    return p;
  };
  u16*   xb       = (u16*)alloc((size_t)Mpad * 128 * 2);   // x, bf16
  u16*   w1t      = (u16*)alloc((size_t)256 * 128 * 2);    // W1^T bf16 [256][128]
  u16*   w2t      = (u16*)alloc((size_t)64 * 256 * 2);     // W2^T bf16 [64][256]
  u16*   xlb1     = (u16*)alloc((size_t)Mpad * 256 * 2);   // x@W1, bf16
  u16*   hb       = (u16*)alloc((size_t)Mpad * 256 * 2);   // ELU output, bf16
  float* asrc1    = (float*)alloc((size_t)Nn * 4 * 4);
  float* adst1    = (float*)alloc((size_t)Nn * 4 * 4);
  float* asrc2    = (float*)alloc((size_t)Nn * 4);
  float* adst2    = (float*)alloc((size_t)Nn * 4);
  int*   deg      = (int*)alloc((size_t)(Ntot + 8) * 4);
  int*   rowptr   = (int*)alloc((size_t)(Ntot + 8) * 4);
  int*   cursor   = (int*)alloc((size_t)(Ntot + 8) * 4);
  int*   partials = (int*)alloc(256 * 4);
  int*   col      = (int*)alloc((size_t)Et * 4);
  u16*   xlb2     = xlb1;  // layer2 h@W2 bf16 [Mpad][64], aliases xlb1

  // --- CSR build + input prep ---
  hipMemsetAsync(deg, 0, (size_t)Ntot * 4, stream);
  count_edges_kernel<<<(Et + 255) / 256, 256, 0, stream>>>(ei, E, Nn, deg);
  scan_partials_kernel<<<NB, 256, 0, stream>>>(deg, partials, Ntot);
  scan_top_kernel<<<1, 256, 0, stream>>>(partials, NB);
  scan_final_kernel<<<NB, 256, 0, stream>>>(deg, partials, rowptr, cursor, Ntot);
  scatter_edges_kernel<<<(Et + 255) / 256, 256, 0, stream>>>(ei, E, Nn, cursor, col);
  {
    int nx4 = Nn * 128 / 4;
    int tot = nx4 + 128 * 256 + 256 * 64;
    cast_prep_kernel<<<(tot + 255) / 256, 256, 0, stream>>>(
        x, xb, nx4, W1, w1t, 128, 256, W2, w2t, 256, 64);
  }

  // --- layer 1 ---
  {
    dim3 grid(MB, 2);
    gemm_mfma_kernel<128><<<grid, 256, 0, stream>>>(xb, w1t, xlb1, Nn, 128, 256);
  }
  alpha_kernel<<<(Nn * 4 + 255) / 256, 256, 0, stream>>>(xlb1, as1, ad1, asrc1, adst1, Nn * 4, 4, 64);
  agg_multi_kernel<<<(Nn + 3) / 4, 256, 0, stream>>>(xlb1, asrc1, adst1, rowptr, col, b1, hb, Nn);

  // --- layer 2 ---
  {
    dim3 grid(MB, 1);
    gemm_mfma_kernel<64><<<grid, 256, 0, stream>>>(hb, w2t, xlb2, Nn, 256, 64);
  }
  alpha_kernel<<<(Nn + 255) / 256, 256, 0, stream>>>(xlb2, as2, ad2, asrc2, adst2, Nn, 1, 64);
  agg_single_kernel<<<(Nn + 3) / 4, 256, 0, stream>>>(xlb2, asrc2, adst2, rowptr, col, b2, out, Nn);
}

// Round 7
// 270.777 us; speedup vs baseline: 1.2535x; 1.2535x over previous
//
#include <hip/hip_runtime.h>
#include <math.h>

// ---------------------------------------------------------------------------
// GAT 2-layer (PyG GATConv eval) on gfx950.
// R7: MLP boost in agg kernels — half-wave/node (agg_multi, uint4 gathers),
//     quarter-wave/node (agg_single), prefetch depth-3, bare v_exp_f32.
// R6: max-free softmax. R5: MFMA bf16 GEMMs. R4: parallel scan.
// ---------------------------------------------------------------------------

typedef unsigned short u16;
typedef short s8v __attribute__((ext_vector_type(8)));    // 8 bf16 (4 VGPR)
typedef float f32x4 __attribute__((ext_vector_type(4)));  // MFMA acc

#define LOG2E 1.4426950408889634f

__device__ __forceinline__ float bflo(unsigned int u) {
  return __builtin_bit_cast(float, u << 16);
}
__device__ __forceinline__ float bfhi(unsigned int u) {
  return __builtin_bit_cast(float, u & 0xffff0000u);
}
__device__ __forceinline__ u16 f2bf(float f) {  // RNE
  unsigned int u = __builtin_bit_cast(unsigned int, f);
  return (u16)((u + 0x7fff + ((u >> 16) & 1)) >> 16);
}

// ---- CSR build ------------------------------------------------------------

__global__ void count_edges_kernel(const int* __restrict__ ei, int E, int Nn,
                                   int* __restrict__ deg) {
  int e = blockIdx.x * blockDim.x + threadIdx.x;
  if (e >= E + Nn) return;
  int dst = (e < E) ? ei[E + e] : (e - E);  // self-loops appended
  atomicAdd(&deg[dst], 1);
}

__global__ void scan_partials_kernel(const int* __restrict__ deg,
                                     int* __restrict__ partials, int Ntot) {
  __shared__ int red[256];
  int t = threadIdx.x;
  int base = blockIdx.x * 1024 + t * 4;
  int s = 0;
  if (base + 3 < Ntot) {
    int4 v = *(const int4*)(deg + base);
    s = v.x + v.y + v.z + v.w;
  } else {
    for (int i = 0; i < 4; ++i)
      if (base + i < Ntot) s += deg[base + i];
  }
  red[t] = s;
  __syncthreads();
  for (int off = 128; off > 0; off >>= 1) {
    if (t < off) red[t] += red[t + off];
    __syncthreads();
  }
  if (t == 0) partials[blockIdx.x] = red[0];
}

__global__ void scan_top_kernel(int* __restrict__ partials, int NB) {
  __shared__ int sh[256];
  int t = threadIdx.x;
  sh[t] = (t < NB) ? partials[t] : 0;
  __syncthreads();
  for (int off = 1; off < 256; off <<= 1) {
    int v = (t >= off) ? sh[t - off] : 0;
    __syncthreads();
    sh[t] += v;
    __syncthreads();
  }
  if (t < NB) partials[t] = (t == 0) ? 0 : sh[t - 1];
}

__global__ void scan_final_kernel(const int* __restrict__ deg,
                                  const int* __restrict__ partials,
                                  int* __restrict__ rowptr,
                                  int* __restrict__ cursor, int Ntot) {
  __shared__ int sums[256];
  int t = threadIdx.x;
  int base = blockIdx.x * 1024 + t * 4;
  int4 v = make_int4(0, 0, 0, 0);
  if (base + 3 < Ntot) {
    v = *(const int4*)(deg + base);
  } else {
    if (base + 0 < Ntot) v.x = deg[base + 0];
    if (base + 1 < Ntot) v.y = deg[base + 1];
    if (base + 2 < Ntot) v.z = deg[base + 2];
    if (base + 3 < Ntot) v.w = deg[base + 3];
  }
  sums[t] = v.x + v.y + v.z + v.w;
  __syncthreads();
  for (int off = 1; off < 256; off <<= 1) {
    int u = (t >= off) ? sums[t - off] : 0;
    __syncthreads();
    sums[t] += u;
    __syncthreads();
  }
  int excl = partials[blockIdx.x] + ((t == 0) ? 0 : sums[t - 1]);
  int4 r;
  r.x = excl;
  r.y = r.x + v.x;
  r.z = r.y + v.y;
  r.w = r.z + v.z;
  if (base + 3 < Ntot) {
    *(int4*)(rowptr + base) = r;
    *(int4*)(cursor + base) = r;
  } else {
    if (base + 0 < Ntot) { rowptr[base + 0] = r.x; cursor[base + 0] = r.x; }
    if (base + 1 < Ntot) { rowptr[base + 1] = r.y; cursor[base + 1] = r.y; }
    if (base + 2 < Ntot) { rowptr[base + 2] = r.z; cursor[base + 2] = r.z; }
    if (base + 3 < Ntot) { rowptr[base + 3] = r.w; cursor[base + 3] = r.w; }
  }
}

__global__ void scatter_edges_kernel(const int* __restrict__ ei, int E, int Nn,
                                     int* __restrict__ cursor, int* __restrict__ col) {
  int e = blockIdx.x * blockDim.x + threadIdx.x;
  if (e >= E + Nn) return;
  int src, dst;
  if (e < E) { src = ei[e]; dst = ei[E + e]; }
  else       { src = dst = e - E; }
  int pos = atomicAdd(&cursor[dst], 1);
  col[pos] = src;
}

// ---- prep: cast x -> bf16; transpose W1, W2 -> [N][K] bf16 ------------------

__global__ void cast_prep_kernel(const float* __restrict__ x, u16* __restrict__ xb,
                                 int nx4,
                                 const float* __restrict__ W1, u16* __restrict__ W1T,
                                 int K1, int N1,
                                 const float* __restrict__ W2, u16* __restrict__ W2T,
                                 int K2, int N2) {
  int i = blockIdx.x * blockDim.x + threadIdx.x;
  if (i < nx4) {
    float4 v = *(const float4*)(x + (size_t)i * 4);
    ushort4 o = make_ushort4(f2bf(v.x), f2bf(v.y), f2bf(v.z), f2bf(v.w));
    *(ushort4*)(xb + (size_t)i * 4) = o;
    return;
  }
  int e = i - nx4;
  int tot1 = K1 * N1;
  if (e < tot1) {
    int k = e / N1, n = e % N1;
    W1T[n * K1 + k] = f2bf(W1[e]);
    return;
  }
  e -= tot1;
  if (e < K2 * N2) {
    int k = e / N2, n = e % N2;
    W2T[n * K2 + k] = f2bf(W2[e]);
  }
}

// ---- MFMA bf16 GEMM: C[M][NC](bf16) = A[Mpad][K](bf16) @ Bt[N][K](bf16)^T ---
// BM=128, BK=32, 256 threads = 4 waves (2x2). Wave tile 64 x (BN/2).

template <int BN>
__global__ __launch_bounds__(256) void gemm_mfma_kernel(
    const u16* __restrict__ A, const u16* __restrict__ Bt,
    u16* __restrict__ C, int M, int K, int NC) {
  constexpr int BM = 128, BK = 32, PK = 40;
  constexpr int NJ = BN / 32;  // frags per wave in N (BN=128 -> 4, 64 -> 2)
  __shared__ short As[BM][PK];
  __shared__ short Bs[BN][PK];

  int tid = threadIdx.x;
  int lane = tid & 63, w = tid >> 6;
  int wm = (w >> 1) * 64, wn = (w & 1) * (BN / 2);
  int bm0 = blockIdx.x * BM, bn0 = blockIdx.y * BN;
  int fr = lane & 15, fk = (lane >> 4) * 8;

  f32x4 acc[4][NJ] = {};

  for (int k0 = 0; k0 < K; k0 += BK) {
#pragma unroll
    for (int p = 0; p < BM * BK / 2048; ++p) {
      int idx = p * 2048 + tid * 8;
      int r = idx / BK, c = idx % BK;
      *(s8v*)&As[r][c] = *(const s8v*)(A + (size_t)(bm0 + r) * K + k0 + c);
    }
#pragma unroll
    for (int p = 0; p < BN * BK / 2048; ++p) {
      int idx = p * 2048 + tid * 8;
      int r = idx / BK, c = idx % BK;
      *(s8v*)&Bs[r][c] = *(const s8v*)(Bt + (size_t)(bn0 + r) * K + k0 + c);
    }
    __syncthreads();

    s8v af[4], bf[NJ];
#pragma unroll
    for (int i = 0; i < 4; ++i)
      af[i] = *(const s8v*)&As[wm + i * 16 + fr][fk];
#pragma unroll
    for (int j = 0; j < NJ; ++j)
      bf[j] = *(const s8v*)&Bs[wn + j * 16 + fr][fk];
#pragma unroll
    for (int i = 0; i < 4; ++i)
#pragma unroll
      for (int j = 0; j < NJ; ++j)
        acc[i][j] = __builtin_amdgcn_mfma_f32_16x16x32_bf16(af[i], bf[j], acc[i][j], 0, 0, 0);
    __syncthreads();
  }

#pragma unroll
  for (int i = 0; i < 4; ++i)
#pragma unroll
    for (int j = 0; j < NJ; ++j)
#pragma unroll
      for (int r = 0; r < 4; ++r) {
        int row = bm0 + wm + i * 16 + (lane >> 4) * 4 + r;
        if (row < M)
          C[(size_t)row * NC + bn0 + wn + j * 16 + fr] = f2bf(acc[i][j][r]);
      }
}

// ---- per-node attention coefficients (bf16 xl) ------------------------------
// outputs pre-scaled by log2(e); lrelu commutes with positive scale.

__global__ void alpha_kernel(const u16* __restrict__ xlb,
                             const float* __restrict__ a_src,
                             const float* __restrict__ a_dst,
                             float* __restrict__ asrc, float* __restrict__ adst,
                             int NH, int H, int C) {
  int idx = blockIdx.x * blockDim.x + threadIdx.x;  // (n,h)
  if (idx >= NH) return;
  int h = idx % H;
  const u16* row = xlb + (size_t)idx * C;
  float ssum = 0.f, dsum = 0.f;
  for (int c = 0; c < C; c += 8) {
    uint4 v = *(const uint4*)(row + c);
    float f[8] = {bflo(v.x), bfhi(v.x), bflo(v.y), bfhi(v.y),
                  bflo(v.z), bfhi(v.z), bflo(v.w), bfhi(v.w)};
#pragma unroll
    for (int j = 0; j < 8; ++j) {
      ssum = fmaf(f[j], a_src[h * C + c + j], ssum);
      dsum = fmaf(f[j], a_dst[h * C + c + j], dsum);
    }
  }
  asrc[idx] = ssum * LOG2E;
  adst[idx] = dsum * LOG2E;
}

// ---- layer-1 aggregation: half-wave (32 lanes) per node, 8 ch/lane ----------
// Max-free softmax; depth-3 prefetch; 2 nodes/wave -> 2x gather streams.

__global__ void agg_multi_kernel(const u16* __restrict__ xlb,
                                 const float* __restrict__ asrc,
                                 const float* __restrict__ adst,
                                 const int* __restrict__ rowptr,
                                 const int* __restrict__ col,
                                 const float* __restrict__ bias,
                                 u16* __restrict__ hb, int Nn) {
  int n = blockIdx.x * 8 + (threadIdx.x >> 5);
  if (n >= Nn) return;
  int lane = threadIdx.x & 31;
  int h = lane >> 3;                          // 8 lanes per head
  float adn = adst[n * 4 + h];
  int beg = rowptr[n], end = rowptr[n + 1];

  float s = 0.f;
  float acc[8] = {};

  float as0 = 0.f, as1 = 0.f, as2 = 0.f;
  uint4 v0 = {}, v1 = {}, v2 = {};
  {
    int sc = col[beg];
    as0 = asrc[sc * 4 + h];
    v0 = *(const uint4*)(xlb + (size_t)sc * 256 + lane * 8);
    if (beg + 1 < end) {
      int c1 = col[beg + 1];
      as1 = asrc[c1 * 4 + h];
      v1 = *(const uint4*)(xlb + (size_t)c1 * 256 + lane * 8);
    }
    if (beg + 2 < end) {
      int c2 = col[beg + 2];
      as2 = asrc[c2 * 4 + h];
      v2 = *(const uint4*)(xlb + (size_t)c2 * 256 + lane * 8);
    }
  }

  for (int i = beg; i < end; ++i) {
    float e = as0 + adn;
    e = fmaxf(e, 0.2f * e);                   // leaky_relu (log2-scaled)
    uint4 vc = v0;
    as0 = as1; v0 = v1;                       // shift pipeline
    as1 = as2; v1 = v2;
    if (i + 3 < end) {
      int sc = col[i + 3];
      as2 = asrc[sc * 4 + h];
      v2 = *(const uint4*)(xlb + (size_t)sc * 256 + lane * 8);
    }
    float w = __builtin_amdgcn_exp2f(e);
    s += w;
    acc[0] = fmaf(w, bflo(vc.x), acc[0]);
    acc[1] = fmaf(w, bfhi(vc.x), acc[1]);
    acc[2] = fmaf(w, bflo(vc.y), acc[2]);
    acc[3] = fmaf(w, bfhi(vc.y), acc[3]);
    acc[4] = fmaf(w, bflo(vc.z), acc[4]);
    acc[5] = fmaf(w, bfhi(vc.z), acc[5]);
    acc[6] = fmaf(w, bflo(vc.w), acc[6]);
    acc[7] = fmaf(w, bfhi(vc.w), acc[7]);
  }
  float inv_s = 1.f / s;

  float4 b0 = *(const float4*)(bias + lane * 8);
  float4 b1f = *(const float4*)(bias + lane * 8 + 4);
  float bb[8] = {b0.x, b0.y, b0.z, b0.w, b1f.x, b1f.y, b1f.z, b1f.w};
  u16 ov[8];
#pragma unroll
  for (int j = 0; j < 8; ++j) {
    float o = fmaf(acc[j], inv_s, bb[j]);
    o = (o > 0.f) ? o : __expf(o) - 1.f;      // ELU
    ov[j] = f2bf(o);
  }
  *(uint4*)(hb + (size_t)n * 256 + lane * 8) = *(uint4*)ov;
}

// ---- layer-2 aggregation: quarter-wave (16 lanes) per node, 4 ch/lane -------

__global__ void agg_single_kernel(const u16* __restrict__ xlb,
                                  const float* __restrict__ asrc,
                                  const float* __restrict__ adst,
                                  const int* __restrict__ rowptr,
                                  const int* __restrict__ col,
                                  const float* __restrict__ bias,
                                  float* __restrict__ out, int Nn) {
  int n = blockIdx.x * 16 + (threadIdx.x >> 4);
  if (n >= Nn) return;
  int lane = threadIdx.x & 15;
  float adn = adst[n];
  int beg = rowptr[n], end = rowptr[n + 1];

  float s = 0.f;
  float acc[4] = {};

  float as0 = 0.f, as1 = 0.f, as2 = 0.f;
  uint2 v0 = {}, v1 = {}, v2 = {};
  {
    int sc = col[beg];
    as0 = asrc[sc];
    v0 = *(const uint2*)(xlb + (size_t)sc * 64 + lane * 4);
    if (beg + 1 < end) {
      int c1 = col[beg + 1];
      as1 = asrc[c1];
      v1 = *(const uint2*)(xlb + (size_t)c1 * 64 + lane * 4);
    }
    if (beg + 2 < end) {
      int c2 = col[beg + 2];
      as2 = asrc[c2];
      v2 = *(const uint2*)(xlb + (size_t)c2 * 64 + lane * 4);
    }
  }

  for (int i = beg; i < end; ++i) {
    float e = as0 + adn;
    e = fmaxf(e, 0.2f * e);
    uint2 vc = v0;
    as0 = as1; v0 = v1;
    as1 = as2; v1 = v2;
    if (i + 3 < end) {
      int sc = col[i + 3];
      as2 = asrc[sc];
      v2 = *(const uint2*)(xlb + (size_t)sc * 64 + lane * 4);
    }
    float w = __builtin_amdgcn_exp2f(e);
    s += w;
    acc[0] = fmaf(w, bflo(vc.x), acc[0]);
    acc[1] = fmaf(w, bfhi(vc.x), acc[1]);
    acc[2] = fmaf(w, bflo(vc.y), acc[2]);
    acc[3] = fmaf(w, bfhi(vc.y), acc[3]);
  }
  float inv_s = 1.f / s;

  const float* bp = bias + lane * 4;
  float4 o;
  o.x = fmaf(acc[0], inv_s, bp[0]);
  o.y = fmaf(acc[1], inv_s, bp[1]);
  o.z = fmaf(acc[2], inv_s, bp[2]);
  o.w = fmaf(acc[3], inv_s, bp[3]);
  *(float4*)(out + (size_t)n * 64 + lane * 4) = o;
}

// ---------------------------------------------------------------------------

extern "C" void kernel_launch(void* const* d_in, const int* in_sizes, int n_in,
                              void* d_out, int out_size, void* d_ws, size_t ws_size,
                              hipStream_t stream) {
  const float* x   = (const float*)d_in[0];
  const int*   ei  = (const int*)d_in[1];
  const float* W1  = (const float*)d_in[2];
  const float* as1 = (const float*)d_in[3];
  const float* ad1 = (const float*)d_in[4];
  const float* b1  = (const float*)d_in[5];
  const float* W2  = (const float*)d_in[6];
  const float* as2 = (const float*)d_in[7];
  const float* ad2 = (const float*)d_in[8];
  const float* b2  = (const float*)d_in[9];
  float* out = (float*)d_out;

  const int Nn = in_sizes[0] / 128;  // 50000
  const int E  = in_sizes[1] / 2;    // 800000
  const int Et = E + Nn;
  const int Ntot = Nn + 1;           // scan domain (virtual deg[Nn]=0)
  const int NB = (Ntot + 1023) / 1024;
  const int MB = (Nn + 127) / 128;   // GEMM row blocks
  const int Mpad = MB * 128;         // padded rows so staging reads stay in-bounds

  char* base = (char*)d_ws;
  size_t off = 0;
  auto alloc = [&](size_t bytes) -> void* {
    void* p = base + off;
    off = (off + bytes + 255) & ~(size_t)255;
    return p;
  };
  u16*   xb       = (u16*)alloc((size_t)Mpad * 128 * 2);   // x, bf16
  u16*   w1t      = (u16*)alloc((size_t)256 * 128 * 2);    // W1^T bf16 [256][128]
  u16*   w2t      = (u16*)alloc((size_t)64 * 256 * 2);     // W2^T bf16 [64][256]
  u16*   xlb1     = (u16*)alloc((size_t)Mpad * 256 * 2);   // x@W1, bf16
  u16*   hb       = (u16*)alloc((size_t)Mpad * 256 * 2);   // ELU output, bf16
  float* asrc1    = (float*)alloc((size_t)Nn * 4 * 4);
  float* adst1    = (float*)alloc((size_t)Nn * 4 * 4);
  float* asrc2    = (float*)alloc((size_t)Nn * 4);
  float* adst2    = (float*)alloc((size_t)Nn * 4);
  int*   deg      = (int*)alloc((size_t)(Ntot + 8) * 4);
  int*   rowptr   = (int*)alloc((size_t)(Ntot + 8) * 4);
  int*   cursor   = (int*)alloc((size_t)(Ntot + 8) * 4);
  int*   partials = (int*)alloc(256 * 4);
  int*   col      = (int*)alloc((size_t)Et * 4);
  u16*   xlb2     = xlb1;  // layer2 h@W2 bf16 [Mpad][64], aliases xlb1

  // --- CSR build + input prep ---
  hipMemsetAsync(deg, 0, (size_t)Ntot * 4, stream);
  count_edges_kernel<<<(Et + 255) / 256, 256, 0, stream>>>(ei, E, Nn, deg);
  scan_partials_kernel<<<NB, 256, 0, stream>>>(deg, partials, Ntot);
  scan_top_kernel<<<1, 256, 0, stream>>>(partials, NB);
  scan_final_kernel<<<NB, 256, 0, stream>>>(deg, partials, rowptr, cursor, Ntot);
  scatter_edges_kernel<<<(Et + 255) / 256, 256, 0, stream>>>(ei, E, Nn, cursor, col);
  {
    int nx4 = Nn * 128 / 4;
    int tot = nx4 + 128 * 256 + 256 * 64;
    cast_prep_kernel<<<(tot + 255) / 256, 256, 0, stream>>>(
        x, xb, nx4, W1, w1t, 128, 256, W2, w2t, 256, 64);
  }

  // --- layer 1 ---
  {
    dim3 grid(MB, 2);
    gemm_mfma_kernel<128><<<grid, 256, 0, stream>>>(xb, w1t, xlb1, Nn, 128, 256);
  }
  alpha_kernel<<<(Nn * 4 + 255) / 256, 256, 0, stream>>>(xlb1, as1, ad1, asrc1, adst1, Nn * 4, 4, 64);
  agg_multi_kernel<<<(Nn + 7) / 8, 256, 0, stream>>>(xlb1, asrc1, adst1, rowptr, col, b1, hb, Nn);

  // --- layer 2 ---
  {
    dim3 grid(MB, 1);
    gemm_mfma_kernel<64><<<grid, 256, 0, stream>>>(hb, w2t, xlb2, Nn, 256, 64);
  }
  alpha_kernel<<<(Nn + 255) / 256, 256, 0, stream>>>(xlb2, as2, ad2, asrc2, adst2, Nn, 1, 64);
  agg_single_kernel<<<(Nn + 15) / 16, 256, 0, stream>>>(xlb2, asrc2, adst2, rowptr, col, b2, out, Nn);
}

// Round 8
// 259.958 us; speedup vs baseline: 1.3057x; 1.0416x over previous
//
#include <hip/hip_runtime.h>
#include <math.h>

// ---------------------------------------------------------------------------
// GAT 2-layer (PyG GATConv eval) on gfx950.
// R8: agg_single -> 8 lanes/node (one uint4 = full 128B row), 8 nodes/wave;
//     agg_multi prefetch depth 4; scan_top folded into scan_final.
// R7: half-wave agg_multi. R6: max-free softmax. R5: MFMA bf16 GEMMs.
// ---------------------------------------------------------------------------

typedef unsigned short u16;
typedef short s8v __attribute__((ext_vector_type(8)));    // 8 bf16 (4 VGPR)
typedef float f32x4 __attribute__((ext_vector_type(4)));  // MFMA acc

#define LOG2E 1.4426950408889634f

__device__ __forceinline__ float bflo(unsigned int u) {
  return __builtin_bit_cast(float, u << 16);
}
__device__ __forceinline__ float bfhi(unsigned int u) {
  return __builtin_bit_cast(float, u & 0xffff0000u);
}
__device__ __forceinline__ u16 f2bf(float f) {  // RNE
  unsigned int u = __builtin_bit_cast(unsigned int, f);
  return (u16)((u + 0x7fff + ((u >> 16) & 1)) >> 16);
}

// ---- CSR build ------------------------------------------------------------

__global__ void count_edges_kernel(const int* __restrict__ ei, int E, int Nn,
                                   int* __restrict__ deg) {
  int e = blockIdx.x * blockDim.x + threadIdx.x;
  if (e >= E + Nn) return;
  int dst = (e < E) ? ei[E + e] : (e - E);  // self-loops appended
  atomicAdd(&deg[dst], 1);
}

__global__ void scan_partials_kernel(const int* __restrict__ deg,
                                     int* __restrict__ partials, int Ntot) {
  __shared__ int red[256];
  int t = threadIdx.x;
  int base = blockIdx.x * 1024 + t * 4;
  int s = 0;
  if (base + 3 < Ntot) {
    int4 v = *(const int4*)(deg + base);
    s = v.x + v.y + v.z + v.w;
  } else {
    for (int i = 0; i < 4; ++i)
      if (base + i < Ntot) s += deg[base + i];
  }
  red[t] = s;
  __syncthreads();
  for (int off = 128; off > 0; off >>= 1) {
    if (t < off) red[t] += red[t + off];
    __syncthreads();
  }
  if (t == 0) partials[blockIdx.x] = red[0];
}

// per-block local scan + block offset (sum of preceding partials) -> rowptr.
__global__ void scan_final_kernel(const int* __restrict__ deg,
                                  const int* __restrict__ partials,
                                  int* __restrict__ rowptr,
                                  int* __restrict__ cursor, int Ntot, int NB) {
  __shared__ int sums[256];
  int t = threadIdx.x;
  int bid = blockIdx.x;
  int base = bid * 1024 + t * 4;
  int4 v = make_int4(0, 0, 0, 0);
  if (base + 3 < Ntot) {
    v = *(const int4*)(deg + base);
  } else {
    if (base + 0 < Ntot) v.x = deg[base + 0];
    if (base + 1 < Ntot) v.y = deg[base + 1];
    if (base + 2 < Ntot) v.z = deg[base + 2];
    if (base + 3 < Ntot) v.w = deg[base + 3];
  }
  sums[t] = v.x + v.y + v.z + v.w;
  __syncthreads();
  for (int off = 1; off < 256; off <<= 1) {
    int u = (t >= off) ? sums[t - off] : 0;
    __syncthreads();
    sums[t] += u;
    __syncthreads();
  }
  int boff = 0;
  for (int j = 0; j < bid; ++j) boff += partials[j];  // <=48 uniform iters
  int excl = boff + ((t == 0) ? 0 : sums[t - 1]);
  int4 r;
  r.x = excl;
  r.y = r.x + v.x;
  r.z = r.y + v.y;
  r.w = r.z + v.z;
  if (base + 3 < Ntot) {
    *(int4*)(rowptr + base) = r;
    *(int4*)(cursor + base) = r;
  } else {
    if (base + 0 < Ntot) { rowptr[base + 0] = r.x; cursor[base + 0] = r.x; }
    if (base + 1 < Ntot) { rowptr[base + 1] = r.y; cursor[base + 1] = r.y; }
    if (base + 2 < Ntot) { rowptr[base + 2] = r.z; cursor[base + 2] = r.z; }
    if (base + 3 < Ntot) { rowptr[base + 3] = r.w; cursor[base + 3] = r.w; }
  }
}

__global__ void scatter_edges_kernel(const int* __restrict__ ei, int E, int Nn,
                                     int* __restrict__ cursor, int* __restrict__ col) {
  int e = blockIdx.x * blockDim.x + threadIdx.x;
  if (e >= E + Nn) return;
  int src, dst;
  if (e < E) { src = ei[e]; dst = ei[E + e]; }
  else       { src = dst = e - E; }
  int pos = atomicAdd(&cursor[dst], 1);
  col[pos] = src;
}

// ---- prep: cast x -> bf16; transpose W1, W2 -> [N][K] bf16 ------------------

__global__ void cast_prep_kernel(const float* __restrict__ x, u16* __restrict__ xb,
                                 int nx4,
                                 const float* __restrict__ W1, u16* __restrict__ W1T,
                                 int K1, int N1,
                                 const float* __restrict__ W2, u16* __restrict__ W2T,
                                 int K2, int N2) {
  int i = blockIdx.x * blockDim.x + threadIdx.x;
  if (i < nx4) {
    float4 v = *(const float4*)(x + (size_t)i * 4);
    ushort4 o = make_ushort4(f2bf(v.x), f2bf(v.y), f2bf(v.z), f2bf(v.w));
    *(ushort4*)(xb + (size_t)i * 4) = o;
    return;
  }
  int e = i - nx4;
  int tot1 = K1 * N1;
  if (e < tot1) {
    int k = e / N1, n = e % N1;
    W1T[n * K1 + k] = f2bf(W1[e]);
    return;
  }
  e -= tot1;
  if (e < K2 * N2) {
    int k = e / N2, n = e % N2;
    W2T[n * K2 + k] = f2bf(W2[e]);
  }
}

// ---- MFMA bf16 GEMM: C[M][NC](bf16) = A[Mpad][K](bf16) @ Bt[N][K](bf16)^T ---
// BM=128, BK=32, 256 threads = 4 waves (2x2). Wave tile 64 x (BN/2).

template <int BN>
__global__ __launch_bounds__(256) void gemm_mfma_kernel(
    const u16* __restrict__ A, const u16* __restrict__ Bt,
    u16* __restrict__ C, int M, int K, int NC) {
  constexpr int BM = 128, BK = 32, PK = 40;
  constexpr int NJ = BN / 32;  // frags per wave in N (BN=128 -> 4, 64 -> 2)
  __shared__ short As[BM][PK];
  __shared__ short Bs[BN][PK];

  int tid = threadIdx.x;
  int lane = tid & 63, w = tid >> 6;
  int wm = (w >> 1) * 64, wn = (w & 1) * (BN / 2);
  int bm0 = blockIdx.x * BM, bn0 = blockIdx.y * BN;
  int fr = lane & 15, fk = (lane >> 4) * 8;

  f32x4 acc[4][NJ] = {};

  for (int k0 = 0; k0 < K; k0 += BK) {
#pragma unroll
    for (int p = 0; p < BM * BK / 2048; ++p) {
      int idx = p * 2048 + tid * 8;
      int r = idx / BK, c = idx % BK;
      *(s8v*)&As[r][c] = *(const s8v*)(A + (size_t)(bm0 + r) * K + k0 + c);
    }
#pragma unroll
    for (int p = 0; p < BN * BK / 2048; ++p) {
      int idx = p * 2048 + tid * 8;
      int r = idx / BK, c = idx % BK;
      *(s8v*)&Bs[r][c] = *(const s8v*)(Bt + (size_t)(bn0 + r) * K + k0 + c);
    }
    __syncthreads();

    s8v af[4], bf[NJ];
#pragma unroll
    for (int i = 0; i < 4; ++i)
      af[i] = *(const s8v*)&As[wm + i * 16 + fr][fk];
#pragma unroll
    for (int j = 0; j < NJ; ++j)
      bf[j] = *(const s8v*)&Bs[wn + j * 16 + fr][fk];
#pragma unroll
    for (int i = 0; i < 4; ++i)
#pragma unroll
      for (int j = 0; j < NJ; ++j)
        acc[i][j] = __builtin_amdgcn_mfma_f32_16x16x32_bf16(af[i], bf[j], acc[i][j], 0, 0, 0);
    __syncthreads();
  }

#pragma unroll
  for (int i = 0; i < 4; ++i)
#pragma unroll
    for (int j = 0; j < NJ; ++j)
#pragma unroll
      for (int r = 0; r < 4; ++r) {
        int row = bm0 + wm + i * 16 + (lane >> 4) * 4 + r;
        if (row < M)
          C[(size_t)row * NC + bn0 + wn + j * 16 + fr] = f2bf(acc[i][j][r]);
      }
}

// ---- per-node attention coefficients (bf16 xl) ------------------------------
// outputs pre-scaled by log2(e); lrelu commutes with positive scale.

__global__ void alpha_kernel(const u16* __restrict__ xlb,
                             const float* __restrict__ a_src,
                             const float* __restrict__ a_dst,
                             float* __restrict__ asrc, float* __restrict__ adst,
                             int NH, int H, int C) {
  int idx = blockIdx.x * blockDim.x + threadIdx.x;  // (n,h)
  if (idx >= NH) return;
  int h = idx % H;
  const u16* row = xlb + (size_t)idx * C;
  float ssum = 0.f, dsum = 0.f;
  for (int c = 0; c < C; c += 8) {
    uint4 v = *(const uint4*)(row + c);
    float f[8] = {bflo(v.x), bfhi(v.x), bflo(v.y), bfhi(v.y),
                  bflo(v.z), bfhi(v.z), bflo(v.w), bfhi(v.w)};
#pragma unroll
    for (int j = 0; j < 8; ++j) {
      ssum = fmaf(f[j], a_src[h * C + c + j], ssum);
      dsum = fmaf(f[j], a_dst[h * C + c + j], dsum);
    }
  }
  asrc[idx] = ssum * LOG2E;
  adst[idx] = dsum * LOG2E;
}

// ---- layer-1 aggregation: half-wave (32 lanes) per node, 8 ch/lane ----------
// Max-free softmax; depth-4 prefetch; 2 nodes/wave.

__global__ void agg_multi_kernel(const u16* __restrict__ xlb,
                                 const float* __restrict__ asrc,
                                 const float* __restrict__ adst,
                                 const int* __restrict__ rowptr,
                                 const int* __restrict__ col,
                                 const float* __restrict__ bias,
                                 u16* __restrict__ hb, int Nn) {
  int n = blockIdx.x * 8 + (threadIdx.x >> 5);
  if (n >= Nn) return;
  int lane = threadIdx.x & 31;
  int h = lane >> 3;                          // 8 lanes per head
  float adn = adst[n * 4 + h];
  int beg = rowptr[n], end = rowptr[n + 1];

  float s = 0.f;
  float acc[8] = {};

  float as0 = 0.f, as1 = 0.f, as2 = 0.f, as3 = 0.f;
  uint4 v0 = {}, v1 = {}, v2 = {}, v3 = {};
  {
    int sc = col[beg];
    as0 = asrc[sc * 4 + h];
    v0 = *(const uint4*)(xlb + (size_t)sc * 256 + lane * 8);
    if (beg + 1 < end) {
      int c1 = col[beg + 1];
      as1 = asrc[c1 * 4 + h];
      v1 = *(const uint4*)(xlb + (size_t)c1 * 256 + lane * 8);
    }
    if (beg + 2 < end) {
      int c2 = col[beg + 2];
      as2 = asrc[c2 * 4 + h];
      v2 = *(const uint4*)(xlb + (size_t)c2 * 256 + lane * 8);
    }
    if (beg + 3 < end) {
      int c3 = col[beg + 3];
      as3 = asrc[c3 * 4 + h];
      v3 = *(const uint4*)(xlb + (size_t)c3 * 256 + lane * 8);
    }
  }

  for (int i = beg; i < end; ++i) {
    float e = as0 + adn;
    e = fmaxf(e, 0.2f * e);                   // leaky_relu (log2-scaled)
    uint4 vc = v0;
    as0 = as1; v0 = v1;                       // shift pipeline
    as1 = as2; v1 = v2;
    as2 = as3; v2 = v3;
    if (i + 4 < end) {
      int sc = col[i + 4];
      as3 = asrc[sc * 4 + h];
      v3 = *(const uint4*)(xlb + (size_t)sc * 256 + lane * 8);
    }
    float w = __builtin_amdgcn_exp2f(e);
    s += w;
    acc[0] = fmaf(w, bflo(vc.x), acc[0]);
    acc[1] = fmaf(w, bfhi(vc.x), acc[1]);
    acc[2] = fmaf(w, bflo(vc.y), acc[2]);
    acc[3] = fmaf(w, bfhi(vc.y), acc[3]);
    acc[4] = fmaf(w, bflo(vc.z), acc[4]);
    acc[5] = fmaf(w, bfhi(vc.z), acc[5]);
    acc[6] = fmaf(w, bflo(vc.w), acc[6]);
    acc[7] = fmaf(w, bfhi(vc.w), acc[7]);
  }
  float inv_s = 1.f / s;

  float4 b0 = *(const float4*)(bias + lane * 8);
  float4 b1f = *(const float4*)(bias + lane * 8 + 4);
  float bb[8] = {b0.x, b0.y, b0.z, b0.w, b1f.x, b1f.y, b1f.z, b1f.w};
  u16 ov[8];
#pragma unroll
  for (int j = 0; j < 8; ++j) {
    float o = fmaf(acc[j], inv_s, bb[j]);
    o = (o > 0.f) ? o : __expf(o) - 1.f;      // ELU
    ov[j] = f2bf(o);
  }
  *(uint4*)(hb + (size_t)n * 256 + lane * 8) = *(uint4*)ov;
}

// ---- layer-2 aggregation: 8 lanes/node, uint4 = full 128B row, depth-3 ------

__global__ void agg_single_kernel(const u16* __restrict__ xlb,
                                  const float* __restrict__ asrc,
                                  const float* __restrict__ adst,
                                  const int* __restrict__ rowptr,
                                  const int* __restrict__ col,
                                  const float* __restrict__ bias,
                                  float* __restrict__ out, int Nn) {
  int n = blockIdx.x * 32 + (threadIdx.x >> 3);
  if (n >= Nn) return;
  int lane = threadIdx.x & 7;                 // 8 lanes, 8 ch each
  float adn = adst[n];
  int beg = rowptr[n], end = rowptr[n + 1];

  float s = 0.f;
  float acc[8] = {};

  float as0 = 0.f, as1 = 0.f, as2 = 0.f;
  uint4 v0 = {}, v1 = {}, v2 = {};
  {
    int sc = col[beg];
    as0 = asrc[sc];
    v0 = *(const uint4*)(xlb + (size_t)sc * 64 + lane * 8);
    if (beg + 1 < end) {
      int c1 = col[beg + 1];
      as1 = asrc[c1];
      v1 = *(const uint4*)(xlb + (size_t)c1 * 64 + lane * 8);
    }
    if (beg + 2 < end) {
      int c2 = col[beg + 2];
      as2 = asrc[c2];
      v2 = *(const uint4*)(xlb + (size_t)c2 * 64 + lane * 8);
    }
  }

  for (int i = beg; i < end; ++i) {
    float e = as0 + adn;
    e = fmaxf(e, 0.2f * e);
    uint4 vc = v0;
    as0 = as1; v0 = v1;                       // shift pipeline
    as1 = as2; v1 = v2;
    if (i + 3 < end) {
      int sc = col[i + 3];
      as2 = asrc[sc];
      v2 = *(const uint4*)(xlb + (size_t)sc * 64 + lane * 8);
    }
    float w = __builtin_amdgcn_exp2f(e);
    s += w;
    acc[0] = fmaf(w, bflo(vc.x), acc[0]);
    acc[1] = fmaf(w, bfhi(vc.x), acc[1]);
    acc[2] = fmaf(w, bflo(vc.y), acc[2]);
    acc[3] = fmaf(w, bfhi(vc.y), acc[3]);
    acc[4] = fmaf(w, bflo(vc.z), acc[4]);
    acc[5] = fmaf(w, bfhi(vc.z), acc[5]);
    acc[6] = fmaf(w, bflo(vc.w), acc[6]);
    acc[7] = fmaf(w, bfhi(vc.w), acc[7]);
  }
  float inv_s = 1.f / s;

  const float* bp = bias + lane * 8;
  float4 o0, o1;
  o0.x = fmaf(acc[0], inv_s, bp[0]);
  o0.y = fmaf(acc[1], inv_s, bp[1]);
  o0.z = fmaf(acc[2], inv_s, bp[2]);
  o0.w = fmaf(acc[3], inv_s, bp[3]);
  o1.x = fmaf(acc[4], inv_s, bp[4]);
  o1.y = fmaf(acc[5], inv_s, bp[5]);
  o1.z = fmaf(acc[6], inv_s, bp[6]);
  o1.w = fmaf(acc[7], inv_s, bp[7]);
  *(float4*)(out + (size_t)n * 64 + lane * 8) = o0;
  *(float4*)(out + (size_t)n * 64 + lane * 8 + 4) = o1;
}

// ---------------------------------------------------------------------------

extern "C" void kernel_launch(void* const* d_in, const int* in_sizes, int n_in,
                              void* d_out, int out_size, void* d_ws, size_t ws_size,
                              hipStream_t stream) {
  const float* x   = (const float*)d_in[0];
  const int*   ei  = (const int*)d_in[1];
  const float* W1  = (const float*)d_in[2];
  const float* as1 = (const float*)d_in[3];
  const float* ad1 = (const float*)d_in[4];
  const float* b1  = (const float*)d_in[5];
  const float* W2  = (const float*)d_in[6];
  const float* as2 = (const float*)d_in[7];
  const float* ad2 = (const float*)d_in[8];
  const float* b2  = (const float*)d_in[9];
  float* out = (float*)d_out;

  const int Nn = in_sizes[0] / 128;  // 50000
  const int E  = in_sizes[1] / 2;    // 800000
  const int Et = E + Nn;
  const int Ntot = Nn + 1;           // scan domain (virtual deg[Nn]=0)
  const int NB = (Ntot + 1023) / 1024;
  const int MB = (Nn + 127) / 128;   // GEMM row blocks
  const int Mpad = MB * 128;         // padded rows so staging reads stay in-bounds

  char* base = (char*)d_ws;
  size_t off = 0;
  auto alloc = [&](size_t bytes) -> void* {
    void* p = base + off;
    off = (off + bytes + 255) & ~(size_t)255;
    return p;
  };
  u16*   xb       = (u16*)alloc((size_t)Mpad * 128 * 2);   // x, bf16
  u16*   w1t      = (u16*)alloc((size_t)256 * 128 * 2);    // W1^T bf16 [256][128]
  u16*   w2t      = (u16*)alloc((size_t)64 * 256 * 2);     // W2^T bf16 [64][256]
  u16*   xlb1     = (u16*)alloc((size_t)Mpad * 256 * 2);   // x@W1, bf16
  u16*   hb       = (u16*)alloc((size_t)Mpad * 256 * 2);   // ELU output, bf16
  float* asrc1    = (float*)alloc((size_t)Nn * 4 * 4);
  float* adst1    = (float*)alloc((size_t)Nn * 4 * 4);
  float* asrc2    = (float*)alloc((size_t)Nn * 4);
  float* adst2    = (float*)alloc((size_t)Nn * 4);
  int*   deg      = (int*)alloc((size_t)(Ntot + 8) * 4);
  int*   rowptr   = (int*)alloc((size_t)(Ntot + 8) * 4);
  int*   cursor   = (int*)alloc((size_t)(Ntot + 8) * 4);
  int*   partials = (int*)alloc(256 * 4);
  int*   col      = (int*)alloc((size_t)Et * 4);
  u16*   xlb2     = xlb1;  // layer2 h@W2 bf16 [Mpad][64], aliases xlb1

  // --- CSR build + input prep ---
  hipMemsetAsync(deg, 0, (size_t)Ntot * 4, stream);
  count_edges_kernel<<<(Et + 255) / 256, 256, 0, stream>>>(ei, E, Nn, deg);
  scan_partials_kernel<<<NB, 256, 0, stream>>>(deg, partials, Ntot);
  scan_final_kernel<<<NB, 256, 0, stream>>>(deg, partials, rowptr, cursor, Ntot, NB);
  scatter_edges_kernel<<<(Et + 255) / 256, 256, 0, stream>>>(ei, E, Nn, cursor, col);
  {
    int nx4 = Nn * 128 / 4;
    int tot = nx4 + 128 * 256 + 256 * 64;
    cast_prep_kernel<<<(tot + 255) / 256, 256, 0, stream>>>(
        x, xb, nx4, W1, w1t, 128, 256, W2, w2t, 256, 64);
  }

  // --- layer 1 ---
  {
    dim3 grid(MB, 2);
    gemm_mfma_kernel<128><<<grid, 256, 0, stream>>>(xb, w1t, xlb1, Nn, 128, 256);
  }
  alpha_kernel<<<(Nn * 4 + 255) / 256, 256, 0, stream>>>(xlb1, as1, ad1, asrc1, adst1, Nn * 4, 4, 64);
  agg_multi_kernel<<<(Nn + 7) / 8, 256, 0, stream>>>(xlb1, asrc1, adst1, rowptr, col, b1, hb, Nn);

  // --- layer 2 ---
  {
    dim3 grid(MB, 1);
    gemm_mfma_kernel<64><<<grid, 256, 0, stream>>>(hb, w2t, xlb2, Nn, 256, 64);
  }
  alpha_kernel<<<(Nn + 255) / 256, 256, 0, stream>>>(xlb2, as2, ad2, asrc2, adst2, Nn, 1, 64);
  agg_single_kernel<<<(Nn + 31) / 32, 256, 0, stream>>>(xlb2, asrc2, adst2, rowptr, col, b2, out, Nn);
}

// Round 9
// 254.004 us; speedup vs baseline: 1.3363x; 1.0234x over previous
//
#include <hip/hip_runtime.h>
#include <math.h>

// ---------------------------------------------------------------------------
// GAT 2-layer (PyG GATConv eval) on gfx950.
// R9: fusion round — gemm1 full-K-resident reading fp32 x directly with
//     alpha1 fused in epilogue (shfl reduce); alpha2 fused into gemm2;
//     W transposes merged into count kernel. 12 -> 9 dispatches.
// R8: 8-lane/node agg_single. R7: half-wave agg_multi. R6: max-free softmax.
// ---------------------------------------------------------------------------

typedef unsigned short u16;
typedef short s8v __attribute__((ext_vector_type(8)));    // 8 bf16 (4 VGPR)
typedef float f32x4 __attribute__((ext_vector_type(4)));  // MFMA acc

#define LOG2E 1.4426950408889634f

__device__ __forceinline__ float bflo(unsigned int u) {
  return __builtin_bit_cast(float, u << 16);
}
__device__ __forceinline__ float bfhi(unsigned int u) {
  return __builtin_bit_cast(float, u & 0xffff0000u);
}
__device__ __forceinline__ u16 f2bf(float f) {  // RNE
  unsigned int u = __builtin_bit_cast(unsigned int, f);
  return (u16)((u + 0x7fff + ((u >> 16) & 1)) >> 16);
}

// ---- CSR count + W transposes (merged, independent ranges) ------------------

__global__ void prep_count_kernel(const int* __restrict__ ei, int E, int Nn,
                                  int* __restrict__ deg,
                                  const float* __restrict__ W1, u16* __restrict__ W1T,
                                  const float* __restrict__ W2, u16* __restrict__ W2T) {
  int i = blockIdx.x * blockDim.x + threadIdx.x;
  int Et = E + Nn;
  if (i < Et) {
    int dst = (i < E) ? ei[E + i] : (i - E);  // self-loops appended
    atomicAdd(&deg[dst], 1);
    return;
  }
  int e = i - Et;
  if (e < 128 * 256) {                        // W1 [128][256] -> W1T [256][128]
    int k = e >> 8, n = e & 255;
    W1T[n * 128 + k] = f2bf(W1[e]);
    return;
  }
  e -= 128 * 256;
  if (e < 256 * 64) {                         // W2 [256][64] -> W2T [64][256]
    int k = e >> 6, n = e & 63;
    W2T[n * 256 + k] = f2bf(W2[e]);
  }
}

__global__ void scan_partials_kernel(const int* __restrict__ deg,
                                     int* __restrict__ partials, int Ntot) {
  __shared__ int red[256];
  int t = threadIdx.x;
  int base = blockIdx.x * 1024 + t * 4;
  int s = 0;
  if (base + 3 < Ntot) {
    int4 v = *(const int4*)(deg + base);
    s = v.x + v.y + v.z + v.w;
  } else {
    for (int i = 0; i < 4; ++i)
      if (base + i < Ntot) s += deg[base + i];
  }
  red[t] = s;
  __syncthreads();
  for (int off = 128; off > 0; off >>= 1) {
    if (t < off) red[t] += red[t + off];
    __syncthreads();
  }
  if (t == 0) partials[blockIdx.x] = red[0];
}

__global__ void scan_final_kernel(const int* __restrict__ deg,
                                  const int* __restrict__ partials,
                                  int* __restrict__ rowptr,
                                  int* __restrict__ cursor, int Ntot, int NB) {
  __shared__ int sums[256];
  int t = threadIdx.x;
  int bid = blockIdx.x;
  int base = bid * 1024 + t * 4;
  int4 v = make_int4(0, 0, 0, 0);
  if (base + 3 < Ntot) {
    v = *(const int4*)(deg + base);
  } else {
    if (base + 0 < Ntot) v.x = deg[base + 0];
    if (base + 1 < Ntot) v.y = deg[base + 1];
    if (base + 2 < Ntot) v.z = deg[base + 2];
    if (base + 3 < Ntot) v.w = deg[base + 3];
  }
  sums[t] = v.x + v.y + v.z + v.w;
  __syncthreads();
  for (int off = 1; off < 256; off <<= 1) {
    int u = (t >= off) ? sums[t - off] : 0;
    __syncthreads();
    sums[t] += u;
    __syncthreads();
  }
  int boff = 0;
  for (int j = 0; j < bid; ++j) boff += partials[j];  // <=48 uniform iters
  int excl = boff + ((t == 0) ? 0 : sums[t - 1]);
  int4 r;
  r.x = excl;
  r.y = r.x + v.x;
  r.z = r.y + v.y;
  r.w = r.z + v.z;
  if (base + 3 < Ntot) {
    *(int4*)(rowptr + base) = r;
    *(int4*)(cursor + base) = r;
  } else {
    if (base + 0 < Ntot) { rowptr[base + 0] = r.x; cursor[base + 0] = r.x; }
    if (base + 1 < Ntot) { rowptr[base + 1] = r.y; cursor[base + 1] = r.y; }
    if (base + 2 < Ntot) { rowptr[base + 2] = r.z; cursor[base + 2] = r.z; }
    if (base + 3 < Ntot) { rowptr[base + 3] = r.w; cursor[base + 3] = r.w; }
  }
}

__global__ void scatter_edges_kernel(const int* __restrict__ ei, int E, int Nn,
                                     int* __restrict__ cursor, int* __restrict__ col) {
  int e = blockIdx.x * blockDim.x + threadIdx.x;
  if (e >= E + Nn) return;
  int src, dst;
  if (e < E) { src = ei[e]; dst = ei[E + e]; }
  else       { src = dst = e - E; }
  int pos = atomicAdd(&cursor[dst], 1);
  col[pos] = src;
}

// ---- GEMM1 fused: xl1 = bf16(x) @ W1, + alpha1 in epilogue ------------------
// Full-K-resident LDS (K=128). Block: 128 rows x 256 cols (2 halves of 128).
// 4 waves 2x2; per half, wave tile 64x64 = exactly one head (C=64).
// PK=136: row stride 272B, /16=17 odd -> 2-way quarter-wave aliasing (free).

__global__ __launch_bounds__(256) void gemm1_fused_kernel(
    const float* __restrict__ x,      // [M][128] fp32
    const u16* __restrict__ w1t,      // [256][128] bf16
    const float* __restrict__ a_src,  // [4][64] fp32
    const float* __restrict__ a_dst,
    u16* __restrict__ C,              // [Mpad][256] bf16
    float* __restrict__ asrc, float* __restrict__ adst,  // [M*4]
    int M) {
  constexpr int PK = 136;
  __shared__ short As[128][PK];
  __shared__ short Bs[128][PK];
  int tid = threadIdx.x;
  int lane = tid & 63, w = tid >> 6;
  int q = lane >> 4, fr = lane & 15;
  int wm = (w >> 1) * 64, wn = (w & 1) * 64;
  int bm0 = blockIdx.x * 128;
  int fk = q * 8;

  // stage A: x fp32 -> bf16 (cast during staging), 128 rows x 128 K
#pragma unroll
  for (int p = 0; p < 16; ++p) {
    int idx = p * 1024 + tid * 4;
    int r = idx >> 7, c = idx & 127;
    float4 v = make_float4(0.f, 0.f, 0.f, 0.f);
    if (bm0 + r < M) v = *(const float4*)(x + (size_t)(bm0 + r) * 128 + c);
    ushort4 o = make_ushort4(f2bf(v.x), f2bf(v.y), f2bf(v.z), f2bf(v.w));
    *(ushort4*)&As[r][c] = o;
  }
  // stage B half 0: w1t rows 0..127
#pragma unroll
  for (int p = 0; p < 8; ++p) {
    int idx = p * 2048 + tid * 8;
    int r = idx >> 7, c = idx & 127;
    *(s8v*)&Bs[r][c] = *(const s8v*)(w1t + (size_t)r * 128 + c);
  }
  __syncthreads();

  for (int nh = 0; nh < 2; ++nh) {
    if (nh == 1) {
      __syncthreads();                         // all done reading Bs half 0
#pragma unroll
      for (int p = 0; p < 8; ++p) {
        int idx = p * 2048 + tid * 8;
        int r = idx >> 7, c = idx & 127;
        *(s8v*)&Bs[r][c] = *(const s8v*)(w1t + (size_t)(128 + r) * 128 + c);
      }
      __syncthreads();
    }
    f32x4 acc[4][4] = {};
#pragma unroll
    for (int ks = 0; ks < 4; ++ks) {
      s8v af[4], bf[4];
#pragma unroll
      for (int i = 0; i < 4; ++i)
        af[i] = *(const s8v*)&As[wm + i * 16 + fr][ks * 32 + fk];
#pragma unroll
      for (int j = 0; j < 4; ++j)
        bf[j] = *(const s8v*)&Bs[wn + j * 16 + fr][ks * 32 + fk];
#pragma unroll
      for (int i = 0; i < 4; ++i)
#pragma unroll
        for (int j = 0; j < 4; ++j)
          acc[i][j] = __builtin_amdgcn_mfma_f32_16x16x32_bf16(af[i], bf[j], acc[i][j], 0, 0, 0);
    }

    // epilogue: head h = 2*nh + wn/64 covers exactly this wave's 64 cols
    int h = nh * 2 + (wn >> 6);
    float asv[4], adv[4];
#pragma unroll
    for (int j = 0; j < 4; ++j) {
      asv[j] = a_src[h * 64 + j * 16 + fr];
      adv[j] = a_dst[h * 64 + j * 16 + fr];
    }
#pragma unroll
    for (int i = 0; i < 4; ++i) {
#pragma unroll
      for (int r = 0; r < 4; ++r) {
        int row = bm0 + wm + i * 16 + q * 4 + r;
        float ps = 0.f, pd = 0.f;
#pragma unroll
        for (int j = 0; j < 4; ++j) {
          ps = fmaf(acc[i][j][r], asv[j], ps);
          pd = fmaf(acc[i][j][r], adv[j], pd);
        }
#pragma unroll
        for (int mmask = 1; mmask < 16; mmask <<= 1) {
          ps += __shfl_xor(ps, mmask, 64);
          pd += __shfl_xor(pd, mmask, 64);
        }
        if (fr == 0 && row < M) {
          asrc[row * 4 + h] = ps * LOG2E;
          adst[row * 4 + h] = pd * LOG2E;
        }
      }
    }
#pragma unroll
    for (int i = 0; i < 4; ++i)
#pragma unroll
      for (int j = 0; j < 4; ++j)
#pragma unroll
        for (int r = 0; r < 4; ++r) {
          int row = bm0 + wm + i * 16 + q * 4 + r;
          if (row < M)
            C[(size_t)row * 256 + nh * 128 + wn + j * 16 + fr] = f2bf(acc[i][j][r]);
        }
  }
}

// ---- GEMM2 fused: xl2 = hb @ W2, + alpha2 in epilogue (LDS cross-wave) ------
// BM=128, BN=64, BK=32 pipeline over K=256. 4 waves 2x2, wave tile 64x32.

__global__ __launch_bounds__(256) void gemm2_fused_kernel(
    const u16* __restrict__ A,        // hb [Mpad][256] bf16
    const u16* __restrict__ Bt,       // w2t [64][256] bf16
    const float* __restrict__ a_src,  // [64]
    const float* __restrict__ a_dst,
    u16* __restrict__ C,              // [Mpad][64] bf16
    float* __restrict__ asrc, float* __restrict__ adst,  // [M]
    int M) {
  constexpr int BM = 128, BN = 64, BK = 32, PK = 40;
  __shared__ short As[BM][PK];
  __shared__ short Bs[BN][PK];
  __shared__ float alds[BM][4];
  int tid = threadIdx.x;
  int lane = tid & 63, w = tid >> 6;
  int q = lane >> 4, fr = lane & 15;
  int wm = (w >> 1) * 64, wn = (w & 1) * 32;
  int bm0 = blockIdx.x * BM;
  int fk = q * 8;

  f32x4 acc[4][2] = {};

  for (int k0 = 0; k0 < 256; k0 += BK) {
#pragma unroll
    for (int p = 0; p < 2; ++p) {
      int idx = p * 2048 + tid * 8;
      int r = idx / BK, c = idx % BK;
      *(s8v*)&As[r][c] = *(const s8v*)(A + (size_t)(bm0 + r) * 256 + k0 + c);
    }
    {
      int idx = tid * 8;
      int r = idx / BK, c = idx % BK;
      if (r < BN)
        *(s8v*)&Bs[r][c] = *(const s8v*)(Bt + (size_t)r * 256 + k0 + c);
    }
    __syncthreads();

    s8v af[4], bf[2];
#pragma unroll
    for (int i = 0; i < 4; ++i)
      af[i] = *(const s8v*)&As[wm + i * 16 + fr][fk];
#pragma unroll
    for (int j = 0; j < 2; ++j)
      bf[j] = *(const s8v*)&Bs[wn + j * 16 + fr][fk];
#pragma unroll
    for (int i = 0; i < 4; ++i)
#pragma unroll
      for (int j = 0; j < 2; ++j)
        acc[i][j] = __builtin_amdgcn_mfma_f32_16x16x32_bf16(af[i], bf[j], acc[i][j], 0, 0, 0);
    __syncthreads();
  }

  // alpha partials: this wave covers cols wn..wn+31 of the single head
  float asv[2], adv[2];
#pragma unroll
  for (int j = 0; j < 2; ++j) {
    asv[j] = a_src[wn + j * 16 + fr];
    adv[j] = a_dst[wn + j * 16 + fr];
  }
#pragma unroll
  for (int i = 0; i < 4; ++i) {
#pragma unroll
    for (int r = 0; r < 4; ++r) {
      int lr = wm + i * 16 + q * 4 + r;
      float ps = 0.f, pd = 0.f;
#pragma unroll
      for (int j = 0; j < 2; ++j) {
        ps = fmaf(acc[i][j][r], asv[j], ps);
        pd = fmaf(acc[i][j][r], adv[j], pd);
      }
#pragma unroll
      for (int mmask = 1; mmask < 16; mmask <<= 1) {
        ps += __shfl_xor(ps, mmask, 64);
        pd += __shfl_xor(pd, mmask, 64);
      }
      if (fr == 0) {
        alds[lr][(w & 1) * 2 + 0] = ps;
        alds[lr][(w & 1) * 2 + 1] = pd;
      }
    }
  }
  // C write (no sync needed with alds path)
#pragma unroll
  for (int i = 0; i < 4; ++i)
#pragma unroll
    for (int j = 0; j < 2; ++j)
#pragma unroll
      for (int r = 0; r < 4; ++r) {
        int row = bm0 + wm + i * 16 + q * 4 + r;
        if (row < M)
          C[(size_t)row * 64 + wn + j * 16 + fr] = f2bf(acc[i][j][r]);
      }
  __syncthreads();
  if (tid < BM) {
    int row = bm0 + tid;
    if (row < M) {
      asrc[row] = (alds[tid][0] + alds[tid][2]) * LOG2E;
      adst[row] = (alds[tid][1] + alds[tid][3]) * LOG2E;
    }
  }
}

// ---- layer-1 aggregation: half-wave (32 lanes) per node, 8 ch/lane ----------
// Max-free softmax; depth-4 prefetch; 2 nodes/wave.

__global__ void agg_multi_kernel(const u16* __restrict__ xlb,
                                 const float* __restrict__ asrc,
                                 const float* __restrict__ adst,
                                 const int* __restrict__ rowptr,
                                 const int* __restrict__ col,
                                 const float* __restrict__ bias,
                                 u16* __restrict__ hb, int Nn) {
  int n = blockIdx.x * 8 + (threadIdx.x >> 5);
  if (n >= Nn) return;
  int lane = threadIdx.x & 31;
  int h = lane >> 3;                          // 8 lanes per head
  float adn = adst[n * 4 + h];
  int beg = rowptr[n], end = rowptr[n + 1];

  float s = 0.f;
  float acc[8] = {};

  float as0 = 0.f, as1 = 0.f, as2 = 0.f, as3 = 0.f;
  uint4 v0 = {}, v1 = {}, v2 = {}, v3 = {};
  {
    int sc = col[beg];
    as0 = asrc[sc * 4 + h];
    v0 = *(const uint4*)(xlb + (size_t)sc * 256 + lane * 8);
    if (beg + 1 < end) {
      int c1 = col[beg + 1];
      as1 = asrc[c1 * 4 + h];
      v1 = *(const uint4*)(xlb + (size_t)c1 * 256 + lane * 8);
    }
    if (beg + 2 < end) {
      int c2 = col[beg + 2];
      as2 = asrc[c2 * 4 + h];
      v2 = *(const uint4*)(xlb + (size_t)c2 * 256 + lane * 8);
    }
    if (beg + 3 < end) {
      int c3 = col[beg + 3];
      as3 = asrc[c3 * 4 + h];
      v3 = *(const uint4*)(xlb + (size_t)c3 * 256 + lane * 8);
    }
  }

  for (int i = beg; i < end; ++i) {
    float e = as0 + adn;
    e = fmaxf(e, 0.2f * e);                   // leaky_relu (log2-scaled)
    uint4 vc = v0;
    as0 = as1; v0 = v1;                       // shift pipeline
    as1 = as2; v1 = v2;
    as2 = as3; v2 = v3;
    if (i + 4 < end) {
      int sc = col[i + 4];
      as3 = asrc[sc * 4 + h];
      v3 = *(const uint4*)(xlb + (size_t)sc * 256 + lane * 8);
    }
    float w = __builtin_amdgcn_exp2f(e);
    s += w;
    acc[0] = fmaf(w, bflo(vc.x), acc[0]);
    acc[1] = fmaf(w, bfhi(vc.x), acc[1]);
    acc[2] = fmaf(w, bflo(vc.y), acc[2]);
    acc[3] = fmaf(w, bfhi(vc.y), acc[3]);
    acc[4] = fmaf(w, bflo(vc.z), acc[4]);
    acc[5] = fmaf(w, bfhi(vc.z), acc[5]);
    acc[6] = fmaf(w, bflo(vc.w), acc[6]);
    acc[7] = fmaf(w, bfhi(vc.w), acc[7]);
  }
  float inv_s = 1.f / s;

  float4 b0 = *(const float4*)(bias + lane * 8);
  float4 b1f = *(const float4*)(bias + lane * 8 + 4);
  float bb[8] = {b0.x, b0.y, b0.z, b0.w, b1f.x, b1f.y, b1f.z, b1f.w};
  u16 ov[8];
#pragma unroll
  for (int j = 0; j < 8; ++j) {
    float o = fmaf(acc[j], inv_s, bb[j]);
    o = (o > 0.f) ? o : __expf(o) - 1.f;      // ELU
    ov[j] = f2bf(o);
  }
  *(uint4*)(hb + (size_t)n * 256 + lane * 8) = *(uint4*)ov;
}

// ---- layer-2 aggregation: 8 lanes/node, uint4 = full 128B row, depth-3 ------

__global__ void agg_single_kernel(const u16* __restrict__ xlb,
                                  const float* __restrict__ asrc,
                                  const float* __restrict__ adst,
                                  const int* __restrict__ rowptr,
                                  const int* __restrict__ col,
                                  const float* __restrict__ bias,
                                  float* __restrict__ out, int Nn) {
  int n = blockIdx.x * 32 + (threadIdx.x >> 3);
  if (n >= Nn) return;
  int lane = threadIdx.x & 7;                 // 8 lanes, 8 ch each
  float adn = adst[n];
  int beg = rowptr[n], end = rowptr[n + 1];

  float s = 0.f;
  float acc[8] = {};

  float as0 = 0.f, as1 = 0.f, as2 = 0.f;
  uint4 v0 = {}, v1 = {}, v2 = {};
  {
    int sc = col[beg];
    as0 = asrc[sc];
    v0 = *(const uint4*)(xlb + (size_t)sc * 64 + lane * 8);
    if (beg + 1 < end) {
      int c1 = col[beg + 1];
      as1 = asrc[c1];
      v1 = *(const uint4*)(xlb + (size_t)c1 * 64 + lane * 8);
    }
    if (beg + 2 < end) {
      int c2 = col[beg + 2];
      as2 = asrc[c2];
      v2 = *(const uint4*)(xlb + (size_t)c2 * 64 + lane * 8);
    }
  }

  for (int i = beg; i < end; ++i) {
    float e = as0 + adn;
    e = fmaxf(e, 0.2f * e);
    uint4 vc = v0;
    as0 = as1; v0 = v1;                       // shift pipeline
    as1 = as2; v1 = v2;
    if (i + 3 < end) {
      int sc = col[i + 3];
      as2 = asrc[sc];
      v2 = *(const uint4*)(xlb + (size_t)sc * 64 + lane * 8);
    }
    float w = __builtin_amdgcn_exp2f(e);
    s += w;
    acc[0] = fmaf(w, bflo(vc.x), acc[0]);
    acc[1] = fmaf(w, bfhi(vc.x), acc[1]);
    acc[2] = fmaf(w, bflo(vc.y), acc[2]);
    acc[3] = fmaf(w, bfhi(vc.y), acc[3]);
    acc[4] = fmaf(w, bflo(vc.z), acc[4]);
    acc[5] = fmaf(w, bfhi(vc.z), acc[5]);
    acc[6] = fmaf(w, bflo(vc.w), acc[6]);
    acc[7] = fmaf(w, bfhi(vc.w), acc[7]);
  }
  float inv_s = 1.f / s;

  const float* bp = bias + lane * 8;
  float4 o0, o1;
  o0.x = fmaf(acc[0], inv_s, bp[0]);
  o0.y = fmaf(acc[1], inv_s, bp[1]);
  o0.z = fmaf(acc[2], inv_s, bp[2]);
  o0.w = fmaf(acc[3], inv_s, bp[3]);
  o1.x = fmaf(acc[4], inv_s, bp[4]);
  o1.y = fmaf(acc[5], inv_s, bp[5]);
  o1.z = fmaf(acc[6], inv_s, bp[6]);
  o1.w = fmaf(acc[7], inv_s, bp[7]);
  *(float4*)(out + (size_t)n * 64 + lane * 8) = o0;
  *(float4*)(out + (size_t)n * 64 + lane * 8 + 4) = o1;
}

// ---------------------------------------------------------------------------

extern "C" void kernel_launch(void* const* d_in, const int* in_sizes, int n_in,
                              void* d_out, int out_size, void* d_ws, size_t ws_size,
                              hipStream_t stream) {
  const float* x   = (const float*)d_in[0];
  const int*   ei  = (const int*)d_in[1];
  const float* W1  = (const float*)d_in[2];
  const float* as1 = (const float*)d_in[3];
  const float* ad1 = (const float*)d_in[4];
  const float* b1  = (const float*)d_in[5];
  const float* W2  = (const float*)d_in[6];
  const float* as2 = (const float*)d_in[7];
  const float* ad2 = (const float*)d_in[8];
  const float* b2  = (const float*)d_in[9];
  float* out = (float*)d_out;

  const int Nn = in_sizes[0] / 128;  // 50000
  const int E  = in_sizes[1] / 2;    // 800000
  const int Et = E + Nn;
  const int Ntot = Nn + 1;           // scan domain (virtual deg[Nn]=0)
  const int NB = (Ntot + 1023) / 1024;
  const int MB = (Nn + 127) / 128;   // GEMM row blocks
  const int Mpad = MB * 128;

  char* base = (char*)d_ws;
  size_t off = 0;
  auto alloc = [&](size_t bytes) -> void* {
    void* p = base + off;
    off = (off + bytes + 255) & ~(size_t)255;
    return p;
  };
  u16*   w1t      = (u16*)alloc((size_t)256 * 128 * 2);    // W1^T bf16 [256][128]
  u16*   w2t      = (u16*)alloc((size_t)64 * 256 * 2);     // W2^T bf16 [64][256]
  u16*   xlb1     = (u16*)alloc((size_t)Mpad * 256 * 2);   // x@W1, bf16
  u16*   hb       = (u16*)alloc((size_t)Mpad * 256 * 2);   // ELU output, bf16
  float* asrc1    = (float*)alloc((size_t)Nn * 4 * 4);
  float* adst1    = (float*)alloc((size_t)Nn * 4 * 4);
  float* asrc2    = (float*)alloc((size_t)Nn * 4);
  float* adst2    = (float*)alloc((size_t)Nn * 4);
  int*   deg      = (int*)alloc((size_t)(Ntot + 8) * 4);
  int*   rowptr   = (int*)alloc((size_t)(Ntot + 8) * 4);
  int*   cursor   = (int*)alloc((size_t)(Ntot + 8) * 4);
  int*   partials = (int*)alloc(256 * 4);
  int*   col      = (int*)alloc((size_t)Et * 4);
  u16*   xlb2     = xlb1;  // layer2 h@W2 bf16 [Mpad][64], aliases xlb1

  // --- CSR build + W prep ---
  hipMemsetAsync(deg, 0, (size_t)Ntot * 4, stream);
  {
    int tot = Et + 128 * 256 + 256 * 64;
    prep_count_kernel<<<(tot + 255) / 256, 256, 0, stream>>>(
        ei, E, Nn, deg, W1, w1t, W2, w2t);
  }
  scan_partials_kernel<<<NB, 256, 0, stream>>>(deg, partials, Ntot);
  scan_final_kernel<<<NB, 256, 0, stream>>>(deg, partials, rowptr, cursor, Ntot, NB);
  scatter_edges_kernel<<<(Et + 255) / 256, 256, 0, stream>>>(ei, E, Nn, cursor, col);

  // --- layer 1 ---
  gemm1_fused_kernel<<<MB, 256, 0, stream>>>(x, w1t, as1, ad1, xlb1, asrc1, adst1, Nn);
  agg_multi_kernel<<<(Nn + 7) / 8, 256, 0, stream>>>(xlb1, asrc1, adst1, rowptr, col, b1, hb, Nn);

  // --- layer 2 ---
  gemm2_fused_kernel<<<MB, 256, 0, stream>>>(hb, w2t, as2, ad2, xlb2, asrc2, adst2, Nn);
  agg_single_kernel<<<(Nn + 31) / 32, 256, 0, stream>>>(xlb2, asrc2, adst2, rowptr, col, b2, out, Nn);
}